// Round 4
// baseline (144.121 us; speedup 1.0000x reference)
//
#include <hip/hip_runtime.h>
#include <math.h>

#define KK 5
#define C_DIM 256
#define LIN 4096
#define B_DIM 4
#define N_PTS 8192
#define PTS 32          // points per MLP block
#define NBUCK (B_DIM * LIN)   // 16384 sort buckets

typedef short short8 __attribute__((ext_vector_type(8)));
typedef float f32x4  __attribute__((ext_vector_type(4)));

__device__ __forceinline__ float leaky(float v) { return v >= 0.0f ? v : 0.2f * v; }
__device__ __forceinline__ float softplus_f(float v) { return v > 20.0f ? v : log1pf(expf(v)); }
__device__ __forceinline__ float bflo(unsigned u) { return __uint_as_float(u << 16); }
__device__ __forceinline__ float bfhi(unsigned u) { return __uint_as_float(u & 0xFFFF0000u); }
__device__ __forceinline__ ushort f2bf(float f) {           // RNE f32 -> bf16 bits
    unsigned u = __float_as_uint(f);
    u += 0x7FFFu + ((u >> 16) & 1u);
    return (ushort)(u >> 16);
}
__device__ __forceinline__ float bf2f(ushort h) { return __uint_as_float((unsigned)h << 16); }
__device__ __forceinline__ int anchor_key(const float* coords, int pt) {
    float x = coords[pt];
    float ix = fminf(fmaxf((x + 1.0f) * 0.5f * (float)(LIN - 1), 0.0f), (float)(LIN - 1));
    return (pt >> 13) * LIN + (int)ix;
}

// ---------------- Kernel 0: transpose + hi/lo-split weights (one-off) -------
__global__ __launch_bounds__(256) void prep_weights(
    const float* __restrict__ W1, const float* __restrict__ Wr,
    ushort* __restrict__ W1t_hi, ushort* __restrict__ W1t_lo,
    ushort* __restrict__ Wrt_hi, ushort* __restrict__ Wrt_lo)
{
    int i = blockIdx.x * 256 + threadIdx.x;
    if (i < 64 * 264) {
        int j = i / 264, k = i % 264;
        float v = (k < 256) ? W1[(size_t)k * 64 + j] : 0.0f;
        ushort hi = f2bf(v);
        W1t_hi[i] = hi;
        W1t_lo[i] = f2bf(v - bf2f(hi));
    } else {
        int i2 = i - 64 * 264;
        if (i2 < 64 * 72) {
            int j = i2 / 72, k = i2 % 72;
            float v = (k < 64) ? Wr[(size_t)k * 64 + j] : 0.0f;
            ushort hi = f2bf(v);
            Wrt_hi[i2] = hi;
            Wrt_lo[i2] = f2bf(v - bf2f(hi));
        }
    }
}

// ---------------- Sort kernels: counting sort of points by anchor texel -----
__global__ __launch_bounds__(256) void sort_count(
    const float* __restrict__ coords, unsigned* __restrict__ hist)
{
    int pt = blockIdx.x * 256 + threadIdx.x;
    atomicAdd(&hist[anchor_key(coords, pt)], 1u);
}

__global__ __launch_bounds__(256) void sort_scan(
    const unsigned* __restrict__ hist, unsigned* __restrict__ offs)
{
    __shared__ unsigned base[256];
    int t = threadIdx.x;
    unsigned s = 0;
    for (int i = 0; i < NBUCK / 256; i++) s += hist[t * (NBUCK / 256) + i];
    base[t] = s;
    __syncthreads();
    if (t == 0) {
        unsigned run = 0;
        for (int i = 0; i < 256; i++) { unsigned v = base[i]; base[i] = run; run += v; }
    }
    __syncthreads();
    unsigned run = base[t];
    for (int i = 0; i < NBUCK / 256; i++) {
        int idx = t * (NBUCK / 256) + i;
        offs[idx] = run;
        run += hist[idx];
    }
}

__global__ __launch_bounds__(256) void sort_scatter(
    const float* __restrict__ coords, unsigned* __restrict__ offs,
    int* __restrict__ perm)
{
    int pt = blockIdx.x * 256 + threadIdx.x;
    unsigned pos = atomicAdd(&offs[anchor_key(coords, pt)], 1u);
    perm[pos] = pt;
}

// ---------------- Kernel 1: transpose feat [B][C][L] -> bf16 feat_t [B][L][C]
__global__ __launch_bounds__(256) void transpose_kernel(
    const float* __restrict__ feat, ushort* __restrict__ feat_t)
{
    __shared__ float tile[32][33];
    int b  = blockIdx.z;
    int l0 = blockIdx.x * 32;
    int c0 = blockIdx.y * 32;
    const float* src = feat + (size_t)b * C_DIM * LIN;
    ushort* dst = feat_t + (size_t)b * LIN * C_DIM;
    int tx = threadIdx.x, ty = threadIdx.y;   // (32, 8)
#pragma unroll
    for (int i = 0; i < 4; i++)
        tile[ty + i * 8][tx] = src[(size_t)(c0 + ty + i * 8) * LIN + (l0 + tx)];
    __syncthreads();
#pragma unroll
    for (int i = 0; i < 4; i++)
        dst[(size_t)(l0 + ty + i * 8) * C_DIM + (c0 + tx)] = f2bf(tile[tx][ty + i * 8]);
}

// ---------------- Kernel 2: MFMA MLP -> params (5 ix + 5 norm weights) ------
__global__ __launch_bounds__(256) void mlp_kernel(
    const ushort* __restrict__ feat_t,
    const float* __restrict__ coords,
    const float* __restrict__ cell,
    const float* __restrict__ W1, const float* __restrict__ b1,
    const float* __restrict__ br,
    const float* __restrict__ W3, const float* __restrict__ b3,
    const ushort* __restrict__ W1t_hi, const ushort* __restrict__ W1t_lo,
    const ushort* __restrict__ Wrt_hi, const ushort* __restrict__ Wrt_lo,
    float* __restrict__ params)
{
    __shared__ ushort Ah[PTS][264], Al[PTS][264];   // anchors hi/lo (33.8 KB)
    __shared__ ushort H1h[PTS][72], H1l[PTS][72];   // h1 hi/lo (9.2 KB)
    __shared__ float  H2[PTS][68];                  // h2 f32 (8.7 KB)
    __shared__ float  outs[PTS][12];
    __shared__ float  xs[PTS], cls[PTS];

    const int t = threadIdx.x;
    const int base = blockIdx.x * PTS;
    const int bb = base >> 13;
    const ushort* fb = feat_t + (size_t)bb * LIN * C_DIM;

    // --- anchor gather: 8 threads/point, 32 channels each, f32 lerp -> hi/lo
    {
        int p = t >> 3, l8 = t & 7;
        int pt = base + p;
        float x = coords[pt];
        float ix = fminf(fmaxf((x + 1.0f) * 0.5f * (float)(LIN - 1), 0.0f), (float)(LIN - 1));
        float x0 = floorf(ix);
        int i0 = min((int)x0, LIN - 1);
        int i1 = min(i0 + 1, LIN - 1);
        float fr = ix - x0, om = 1.0f - fr;
        if (l8 == 0) { xs[p] = x; cls[p] = cell[pt]; }
        const ushort* r0 = fb + (size_t)i0 * C_DIM;
        const ushort* r1 = fb + (size_t)i1 * C_DIM;
#pragma unroll
        for (int q = 0; q < 4; q++) {
            int c = l8 * 8 + q * 64;
            uint4 u0 = *(const uint4*)(r0 + c);
            uint4 u1 = *(const uint4*)(r1 + c);
            float v[8];
            v[0] = bflo(u0.x) * om + bflo(u1.x) * fr;
            v[1] = bfhi(u0.x) * om + bfhi(u1.x) * fr;
            v[2] = bflo(u0.y) * om + bflo(u1.y) * fr;
            v[3] = bfhi(u0.y) * om + bfhi(u1.y) * fr;
            v[4] = bflo(u0.z) * om + bflo(u1.z) * fr;
            v[5] = bfhi(u0.z) * om + bfhi(u1.z) * fr;
            v[6] = bflo(u0.w) * om + bflo(u1.w) * fr;
            v[7] = bfhi(u0.w) * om + bfhi(u1.w) * fr;
            ushort hv[8], lv[8];
#pragma unroll
            for (int e = 0; e < 8; e++) {
                hv[e] = f2bf(v[e]);
                lv[e] = f2bf(v[e] - bf2f(hv[e]));
            }
            *(uint4*)&Ah[p][c] = *(uint4*)hv;
            *(uint4*)&Al[p][c] = *(uint4*)lv;
        }
    }
    __syncthreads();

    const int wave = t >> 6, lane = t & 63;
    const int cr = lane & 15;       // A-frag row / B-frag col / C-frag col
    const int kb = lane >> 4;       // k sub-chunk
    const int jcol = wave * 16 + cr;

    // --- layer 1: [32 x 256] @ [256 x 64] via 3-MFMA hi/lo ------------------
    f32x4 acc0 = {0.f, 0.f, 0.f, 0.f}, acc1 = acc0;
    {
        const ushort* B1h = W1t_hi + (size_t)jcol * 264;
        const ushort* B1l = W1t_lo + (size_t)jcol * 264;
#pragma unroll
        for (int k0 = 0; k0 < 256; k0 += 32) {
            int ko = k0 + kb * 8;
            short8 a0h = *(const short8*)&Ah[cr][ko];
            short8 a0l = *(const short8*)&Al[cr][ko];
            short8 a1h = *(const short8*)&Ah[16 + cr][ko];
            short8 a1l = *(const short8*)&Al[16 + cr][ko];
            short8 bh = *(const short8*)(B1h + ko);
            short8 bl = *(const short8*)(B1l + ko);
            acc0 = __builtin_amdgcn_mfma_f32_16x16x32_bf16(a0h, bh, acc0, 0, 0, 0);
            acc0 = __builtin_amdgcn_mfma_f32_16x16x32_bf16(a0h, bl, acc0, 0, 0, 0);
            acc0 = __builtin_amdgcn_mfma_f32_16x16x32_bf16(a0l, bh, acc0, 0, 0, 0);
            acc1 = __builtin_amdgcn_mfma_f32_16x16x32_bf16(a1h, bh, acc1, 0, 0, 0);
            acc1 = __builtin_amdgcn_mfma_f32_16x16x32_bf16(a1h, bl, acc1, 0, 0, 0);
            acc1 = __builtin_amdgcn_mfma_f32_16x16x32_bf16(a1l, bh, acc1, 0, 0, 0);
        }
    }
    float h1a[4], h1b[4];
    {
        float wx = W1[(size_t)256 * 64 + jcol];
        float wc = W1[(size_t)257 * 64 + jcol];
        float bb1 = b1[jcol];
#pragma unroll
        for (int r = 0; r < 4; r++) {
            int p0 = kb * 4 + r;
            float v0 = leaky(acc0[r] + xs[p0] * wx + cls[p0] * wc + bb1);
            h1a[r] = v0;
            ushort hi0 = f2bf(v0);
            H1h[p0][jcol] = hi0;
            H1l[p0][jcol] = f2bf(v0 - bf2f(hi0));
            int p1 = 16 + p0;
            float v1 = leaky(acc1[r] + xs[p1] * wx + cls[p1] * wc + bb1);
            h1b[r] = v1;
            ushort hi1 = f2bf(v1);
            H1h[p1][jcol] = hi1;
            H1l[p1][jcol] = f2bf(v1 - bf2f(hi1));
        }
    }
    __syncthreads();

    // --- layer 2 (residual): [32 x 64] @ [64 x 64] --------------------------
    f32x4 r0 = {0.f, 0.f, 0.f, 0.f}, r1 = r0;
    {
        const ushort* B2h = Wrt_hi + (size_t)jcol * 72;
        const ushort* B2l = Wrt_lo + (size_t)jcol * 72;
#pragma unroll
        for (int k0 = 0; k0 < 64; k0 += 32) {
            int ko = k0 + kb * 8;
            short8 a0h = *(const short8*)&H1h[cr][ko];
            short8 a0l = *(const short8*)&H1l[cr][ko];
            short8 a1h = *(const short8*)&H1h[16 + cr][ko];
            short8 a1l = *(const short8*)&H1l[16 + cr][ko];
            short8 bh = *(const short8*)(B2h + ko);
            short8 bl = *(const short8*)(B2l + ko);
            r0 = __builtin_amdgcn_mfma_f32_16x16x32_bf16(a0h, bh, r0, 0, 0, 0);
            r0 = __builtin_amdgcn_mfma_f32_16x16x32_bf16(a0h, bl, r0, 0, 0, 0);
            r0 = __builtin_amdgcn_mfma_f32_16x16x32_bf16(a0l, bh, r0, 0, 0, 0);
            r1 = __builtin_amdgcn_mfma_f32_16x16x32_bf16(a1h, bh, r1, 0, 0, 0);
            r1 = __builtin_amdgcn_mfma_f32_16x16x32_bf16(a1h, bl, r1, 0, 0, 0);
            r1 = __builtin_amdgcn_mfma_f32_16x16x32_bf16(a1l, bh, r1, 0, 0, 0);
        }
        float brv = br[jcol];
#pragma unroll
        for (int r = 0; r < 4; r++) {
            int p0 = kb * 4 + r;
            H2[p0][jcol]      = leaky(h1a[r] + r0[r] + brv);
            H2[16 + p0][jcol] = leaky(h1b[r] + r1[r] + brv);
        }
    }
    __syncthreads();

    // --- layer 3: 12 outputs, f32 VALU --------------------------------------
    {
        int p = t & 31;
        int o = t >> 5;                 // 0..7
        for (int oo = o; oo < 12; oo += 8) {
            float acc = b3[oo];
#pragma unroll 4
            for (int l = 0; l < 64; l++)
                acc = fmaf(H2[p][l], W3[(size_t)l * 12 + oo], acc);
            outs[p][oo] = acc;
        }
    }
    __syncthreads();

    // --- epilogue: sample coords + normalized weights -----------------------
    if (t < PTS) {
        int pt = base + t;
        float x = xs[t];
        float r = softplus_f(outs[t][0]) + 0.3f;
        r = fminf(fmaxf(r, 0.3f), 2.0f);
        float sg = softplus_f(outs[t][1]) + 0.5f;
        sg = fminf(fmaxf(sg, 0.5f), 3.0f);
        float denom = (sg * 2.0f) * (sg * 2.0f) + 1e-8f;
        const float BASEv[KK] = {-2.0f, -1.0f, 0.0f, 1.0f, 2.0f};
        float ixk[KK], wk[KK];
        float wsum = 0.0f;
#pragma unroll
        for (int k = 0; k < KK; k++) {
            float res = tanhf(outs[t][2 + k]) * 0.5f;
            float off = r * BASEv[k] + res;
            float dx = x + off * (2.0f / (float)(LIN - 1));
            float ix = (dx + 1.0f) * 0.5f * (float)(LIN - 1);
            ix = fminf(fmaxf(ix, 0.0f), (float)(LIN - 1));
            float gate = outs[t][2 + KK + k];
            float wgeo = expf(-0.5f * off * off / denom);
            float sig = 1.0f / (1.0f + expf(-gate));
            float w = wgeo * sig;
            ixk[k] = ix; wk[k] = w; wsum += w;
        }
        float inv = 1.0f / (wsum + 1e-8f);
        float* pp = params + (size_t)pt * 10;
#pragma unroll
        for (int k = 0; k < KK; k++) {
            pp[k]     = ixk[k];
            pp[5 + k] = wk[k] * inv;
        }
    }
}

// ---------------- Kernel 3: deformed gather in anchor-sorted order ----------
__global__ __launch_bounds__(256) void gather_kernel(
    const ushort* __restrict__ feat_t, const float* __restrict__ params,
    const int* __restrict__ perm, float* __restrict__ out)
{
    int t = threadIdx.x;
    int p = t >> 5;
    int lane = t & 31;
    int pt = perm[blockIdx.x * 8 + p];
    int b = pt >> 13;
    const float* pp = params + (size_t)pt * 10;
    const ushort* fb = feat_t + (size_t)b * LIN * C_DIM;
    int c = lane * 8;
    float a0 = 0, a1 = 0, a2 = 0, a3 = 0, a4 = 0, a5 = 0, a6 = 0, a7 = 0;
#pragma unroll
    for (int k = 0; k < KK; k++) {
        float ix = pp[k];
        float w  = pp[5 + k];
        float x0 = floorf(ix);
        int i0 = (int)x0;
        int i1 = min(i0 + 1, LIN - 1);
        float fr = ix - x0;
        uint4 u0 = *(const uint4*)(fb + (size_t)i0 * C_DIM + c);
        uint4 u1 = *(const uint4*)(fb + (size_t)i1 * C_DIM + c);
        float w0 = w * (1.0f - fr), w1 = w * fr;
        a0 = fmaf(w0, bflo(u0.x), fmaf(w1, bflo(u1.x), a0));
        a1 = fmaf(w0, bfhi(u0.x), fmaf(w1, bfhi(u1.x), a1));
        a2 = fmaf(w0, bflo(u0.y), fmaf(w1, bflo(u1.y), a2));
        a3 = fmaf(w0, bfhi(u0.y), fmaf(w1, bfhi(u1.y), a3));
        a4 = fmaf(w0, bflo(u0.z), fmaf(w1, bflo(u1.z), a4));
        a5 = fmaf(w0, bfhi(u0.z), fmaf(w1, bfhi(u1.z), a5));
        a6 = fmaf(w0, bflo(u0.w), fmaf(w1, bflo(u1.w), a6));
        a7 = fmaf(w0, bfhi(u0.w), fmaf(w1, bfhi(u1.w), a7));
    }
    float* op = out + (size_t)pt * C_DIM + c;
    *(float4*)op       = make_float4(a0, a1, a2, a3);
    *(float4*)(op + 4) = make_float4(a4, a5, a6, a7);
}

extern "C" void kernel_launch(void* const* d_in, const int* in_sizes, int n_in,
                              void* d_out, int out_size, void* d_ws, size_t ws_size,
                              hipStream_t stream) {
    const float* feat   = (const float*)d_in[0];
    const float* coords = (const float*)d_in[1];
    const float* cell   = (const float*)d_in[2];
    const float* W1 = (const float*)d_in[3];
    const float* b1 = (const float*)d_in[4];
    const float* Wr = (const float*)d_in[5];
    const float* br = (const float*)d_in[6];
    const float* W3 = (const float*)d_in[7];
    const float* b3 = (const float*)d_in[8];
    float* out = (float*)d_out;

    char* ws = (char*)d_ws;
    ushort* feat_t = (ushort*)ws;                       // 33.55 MB
    ws += (size_t)B_DIM * LIN * C_DIM * 2;
    float* params = (float*)ws;                         // 1.31 MB
    ws += (size_t)B_DIM * N_PTS * 10 * 4;
    ushort* W1t_hi = (ushort*)ws; ws += 64 * 264 * 2;
    ushort* W1t_lo = (ushort*)ws; ws += 64 * 264 * 2;
    ushort* Wrt_hi = (ushort*)ws; ws += 64 * 72 * 2;
    ushort* Wrt_lo = (ushort*)ws; ws += 64 * 72 * 2;
    ws = (char*)(((uintptr_t)ws + 255) & ~(uintptr_t)255);
    unsigned* hist = (unsigned*)ws; ws += NBUCK * 4;    // 64 KB
    unsigned* offs = (unsigned*)ws; ws += NBUCK * 4;    // 64 KB
    int* perm      = (int*)ws;      ws += (size_t)B_DIM * N_PTS * 4;  // 128 KB

    int nPts = B_DIM * N_PTS;

    hipMemsetAsync(hist, 0, NBUCK * 4, stream);
    sort_count<<<nPts / 256, 256, 0, stream>>>(coords, hist);
    sort_scan<<<1, 256, 0, stream>>>(hist, offs);
    sort_scatter<<<nPts / 256, 256, 0, stream>>>(coords, offs, perm);

    prep_weights<<<(64 * 264 + 64 * 72 + 255) / 256, 256, 0, stream>>>(
        W1, Wr, W1t_hi, W1t_lo, Wrt_hi, Wrt_lo);

    dim3 tb(32, 8);
    dim3 tg(LIN / 32, C_DIM / 32, B_DIM);
    transpose_kernel<<<tg, tb, 0, stream>>>(feat, feat_t);

    mlp_kernel<<<nPts / PTS, 256, 0, stream>>>(feat_t, coords, cell,
                                               W1, b1, br, W3, b3,
                                               W1t_hi, W1t_lo, Wrt_hi, Wrt_lo,
                                               params);

    gather_kernel<<<nPts / 8, 256, 0, stream>>>(feat_t, params, perm, out);
}